// Round 8
// baseline (228.414 us; speedup 1.0000x reference)
//
#include <hip/hip_runtime.h>

// LIF forward: X [B, T, N] fp32 -> spikes [B, T, N] fp32. B=128,T=32,N=8192.
//   mem = mem + (x - mem)/2 ; spike = (mem-1 > 0) ; mem = spike ? 0 : mem
// Memory-bound: 268 MB traffic -> ~42.5 us floor at 6.3 TB/s copy ceiling.
// R1: float4, MLP~2: 85.5 us, 2.55 TB/s. R2: dbuf collapsed, neutral.
// R3: float2 full occupancy: ~74 us, 2.9 TB/s. R4: sched_barrier sunk, neutral.
// R5: float2 + 32 separate volatile-asm loads + separate waitcnt: ~74 us.
// R7: float4 version FAILED correctness: compiler may insert v_movs of load
//     dest regs BETWEEN separate asm statements, i.e. before the waitcnt --
//     reads stale registers (R5 only passed by scheduling luck).
// R8: ONE asm block = 16 global_load_dwordx4 + s_waitcnt vmcnt(0) inside.
//     Nothing can interleave inside an asm block -> race impossible.
//     Tests width(16B/lane) x MLP(16-deep, 16KB/wave in flight) together.

#define T_STEPS 32
#define N4 2048            // N/4
#define TN4 (T_STEPS * N4)
#define DEPTH 16           // loads per burst; 2 bursts cover T=32

// one LIF scan step on a float4, emits the spike store at row j
#define STEP(xv, j) do {                                           \
    m0 = m0 + ((xv).x - m0) * 0.5f;                                \
    m1 = m1 + ((xv).y - m1) * 0.5f;                                \
    m2 = m2 + ((xv).z - m2) * 0.5f;                                \
    m3 = m3 + ((xv).w - m3) * 0.5f;                                \
    float4 s;                                                      \
    s.x = (m0 - 1.0f > 0.0f) ? 1.0f : 0.0f;                        \
    s.y = (m1 - 1.0f > 0.0f) ? 1.0f : 0.0f;                        \
    s.z = (m2 - 1.0f > 0.0f) ? 1.0f : 0.0f;                        \
    s.w = (m3 - 1.0f > 0.0f) ? 1.0f : 0.0f;                        \
    m0 = (s.x != 0.0f) ? 0.0f : m0;                                \
    m1 = (s.y != 0.0f) ? 0.0f : m1;                                \
    m2 = (s.z != 0.0f) ? 0.0f : m2;                                \
    m3 = (s.w != 0.0f) ? 0.0f : m3;                                \
    po[(size_t)(j) * (size_t)N4] = s;                              \
} while (0)

__global__ __launch_bounds__(256) void lif_fwd_kernel(
    const float4* __restrict__ X, float4* __restrict__ out)
{
    const int idx = blockIdx.x * blockDim.x + threadIdx.x;  // over B * N4
    const int b = idx >> 11;           // / N4
    const int n = idx & (N4 - 1);
    const size_t base = (size_t)b * (size_t)TN4 + (size_t)n;

    const float4* p = X + base;
    float4* po = out + base;

    float m0 = 0.f, m1 = 0.f, m2 = 0.f, m3 = 0.f;
    float4 x0, x1, x2, x3, x4, x5, x6, x7,
           x8, x9, x10, x11, x12, x13, x14, x15;

#pragma unroll
    for (int half = 0; half < 2; ++half) {
        // ---- 16 loads + drain in ONE asm block: compiler cannot touch the
        // dest registers until after the s_waitcnt. Earlyclobber outputs
        // keep dests disjoint from the 16 address pairs. ----
        asm volatile(
            "global_load_dwordx4 %0, %16, off\n\t"
            "global_load_dwordx4 %1, %17, off\n\t"
            "global_load_dwordx4 %2, %18, off\n\t"
            "global_load_dwordx4 %3, %19, off\n\t"
            "global_load_dwordx4 %4, %20, off\n\t"
            "global_load_dwordx4 %5, %21, off\n\t"
            "global_load_dwordx4 %6, %22, off\n\t"
            "global_load_dwordx4 %7, %23, off\n\t"
            "global_load_dwordx4 %8, %24, off\n\t"
            "global_load_dwordx4 %9, %25, off\n\t"
            "global_load_dwordx4 %10, %26, off\n\t"
            "global_load_dwordx4 %11, %27, off\n\t"
            "global_load_dwordx4 %12, %28, off\n\t"
            "global_load_dwordx4 %13, %29, off\n\t"
            "global_load_dwordx4 %14, %30, off\n\t"
            "global_load_dwordx4 %15, %31, off\n\t"
            "s_waitcnt vmcnt(0)"
            : "=&v"(x0), "=&v"(x1), "=&v"(x2), "=&v"(x3),
              "=&v"(x4), "=&v"(x5), "=&v"(x6), "=&v"(x7),
              "=&v"(x8), "=&v"(x9), "=&v"(x10), "=&v"(x11),
              "=&v"(x12), "=&v"(x13), "=&v"(x14), "=&v"(x15)
            : "v"(p +  0 * (size_t)N4), "v"(p +  1 * (size_t)N4),
              "v"(p +  2 * (size_t)N4), "v"(p +  3 * (size_t)N4),
              "v"(p +  4 * (size_t)N4), "v"(p +  5 * (size_t)N4),
              "v"(p +  6 * (size_t)N4), "v"(p +  7 * (size_t)N4),
              "v"(p +  8 * (size_t)N4), "v"(p +  9 * (size_t)N4),
              "v"(p + 10 * (size_t)N4), "v"(p + 11 * (size_t)N4),
              "v"(p + 12 * (size_t)N4), "v"(p + 13 * (size_t)N4),
              "v"(p + 14 * (size_t)N4), "v"(p + 15 * (size_t)N4)
            : "memory");

        // ---- serial scan in registers, fire-and-forget dwordx4 stores ----
        STEP(x0, 0);   STEP(x1, 1);   STEP(x2, 2);   STEP(x3, 3);
        STEP(x4, 4);   STEP(x5, 5);   STEP(x6, 6);   STEP(x7, 7);
        STEP(x8, 8);   STEP(x9, 9);   STEP(x10, 10); STEP(x11, 11);
        STEP(x12, 12); STEP(x13, 13); STEP(x14, 14); STEP(x15, 15);

        p  += (size_t)DEPTH * (size_t)N4;
        po += (size_t)DEPTH * (size_t)N4;
    }
}

extern "C" void kernel_launch(void* const* d_in, const int* in_sizes, int n_in,
                              void* d_out, int out_size, void* d_ws, size_t ws_size,
                              hipStream_t stream) {
    const float4* X = (const float4*)d_in[0];
    float4* out = (float4*)d_out;

    const int total = in_sizes[0];          // B*T*N = 33554432
    const int B = total / (T_STEPS * 8192); // 128
    const int nthreads = B * N4;            // 262144

    const int block = 256;
    const int grid = (nthreads + block - 1) / block;  // 1024

    lif_fwd_kernel<<<grid, block, 0, stream>>>(X, out);
}